// Round 8
// baseline (52.334 us; speedup 1.0000x reference)
//
#include <hip/hip_runtime.h>
#include <math.h>

#define HDIM 32
#define NSTEPS 32
#define NSECANT 8
#define RADIUSV 1.0f
#define NEARV 0.5f
#define TAUV 0.5f
#define EPSV 1e-6f

typedef float f2 __attribute__((ext_vector_type(2)));

__global__ __launch_bounds__(256, 2) void unisurf_kernel(
    const float* __restrict__ cam_loc,   // [3]
    const float* __restrict__ ray_dirs,  // [P*3]
    const float* __restrict__ W1,        // [3*HDIM]
    const float* __restrict__ b1,        // [HDIM]
    const float* __restrict__ W2,        // [HDIM]
    const float* __restrict__ b2,        // [1]
    float* __restrict__ out,             // [2*P]: d_pred then occ_surf
    int P)
{
    __shared__ float4 sW[HDIM];   // (w0, w1, w2, b1) per hidden unit
    __shared__ float  sCW[HDIM];  // cam·W1 + b1  (ray-independent)
    __shared__ float  sW2[HDIM];
    __shared__ float  sB2;
    __shared__ float  sAB[NSTEPS][256][2];   // per-thread PWL event arrays (A,B)

    const int tid = threadIdx.x;

    // cooperative zero of the event arrays (16384 floats = 4096 float4)
    {
        float4* p4 = (float4*)&sAB[0][0][0];
        #pragma unroll
        for (int i = 0; i < 16; ++i)
            p4[tid + i * 256] = make_float4(0.f, 0.f, 0.f, 0.f);
    }
    if (tid < HDIM) {
        float c0 = cam_loc[0], c1 = cam_loc[1], c2l = cam_loc[2];
        float4 w4 = make_float4(W1[tid], W1[HDIM + tid], W1[2 * HDIM + tid], b1[tid]);
        sW[tid] = w4;
        sCW[tid] = c0 * w4.x + c1 * w4.y + c2l * w4.z + w4.w;
        sW2[tid] = W2[tid];
        if (tid == 0) sB2 = b2[0];
    }
    __syncthreads();

    const int r = blockIdx.x * blockDim.x + tid;
    const int rc = (r < P) ? r : (P - 1);        // clamp so barriers stay uniform

    // camera (wave-uniform)
    const float cx = cam_loc[0], cy = cam_loc[1], cz = cam_loc[2];

    // ray load + fast normalize
    float dx = ray_dirs[3 * rc + 0];
    float dy = ray_dirs[3 * rc + 1];
    float dz = ray_dirs[3 * rc + 2];
    float inv = __builtin_amdgcn_rsqf(dx * dx + dy * dy + dz * dz);
    float rx = dx * inv, ry = dy * inv, rz = dz * inv;

    // sphere intersection
    float rcd = rx * cx + ry * cy + rz * cz;
    float c2  = cx * cx + cy * cy + cz * cz;
    float us  = rcd * rcd - (c2 - RADIUSV * RADIUSV);
    bool  mask_int = us > 0.0f;
    float s_sq = mask_int ? sqrtf(us) : 0.0f;
    float far_raw = mask_int ? fmaxf(s_sq - rcd, 0.0f) : 0.0f;
    float farv = fmaxf(far_raw, NEARV + EPSV);

    // per-ray factored MLP: a_h(d) = cW[h] + d*rW[h]; logit = Σ relu(a)*w2 + B2
    f2 rW[HDIM / 2], cW[HDIM / 2], w2[HDIM / 2];
    #pragma unroll
    for (int h = 0; h < HDIM / 2; ++h) {
        float4 wa = sW[2 * h], wb = sW[2 * h + 1];
        rW[h] = (f2){rx * wa.x + ry * wa.y + rz * wa.z,
                     rx * wb.x + ry * wb.y + rz * wb.z};
        cW[h] = (f2){sCW[2 * h], sCW[2 * h + 1]};
        w2[h] = (f2){sW2[2 * h], sW2[2 * h + 1]};
    }
    const float B2 = sB2;
    const f2 z2 = (f2){0.0f, 0.0f};

    const float STEPC = 0.03225806451612903f;  // fl(1/31)

    // ---- PWL event scatter: logit(s) = C0 + C1*s + Σ_{k<=s}(A[k]*s + B[k]) ----
    const float DD = (farv - NEARV) * STEPC;   // per-step d increment
    float C0 = B2, C1 = 0.0f;
    #pragma unroll
    for (int h = 0; h < HDIM / 2; ++h) {
        #pragma unroll
        for (int e = 0; e < 2; ++e) {
            float rw = e ? rW[h].y : rW[h].x;
            float cw = e ? cW[h].y : cW[h].x;
            float q  = e ? w2[h].y : w2[h].x;
            float alpha = fmaf(NEARV, rw, cw);   // a at s=0
            float rho   = rw * DD;               // per-step slope of a
            float qa = q * alpha;
            float qr = q * rho;
            // flip position sigma = -alpha/rho (steps); exact cancel: -q*rho*sigma = q*alpha
            float sig = -alpha * __builtin_amdgcn_rcpf(rho);
            float scl = fminf(fmaxf(sig, -1.0f), 33.0f);   // NaN -> -1
            int   k   = (int)ceilf(scl);
            bool rpos = rho >= 0.0f;             // unit turns ON at k (else OFF at k)
            bool fold = rpos ? (k <= 0) : (k >= 1);
            bool inr  = (k >= 1) && (k <= 31);
            float sbar = rpos ? 1.0f : -1.0f;
            C0 += fold ? qa : 0.0f;
            C1 += fold ? qr : 0.0f;
            float av = inr ? sbar * qr : 0.0f;
            float bv = inr ? sbar * qa : 0.0f;
            int   ks = inr ? k : 1;              // dump zeros into slot 1
            atomicAdd(&sAB[ks][tid][0], av);
            atomicAdd(&sAB[ks][tid][1], bv);
        }
    }
    __syncthreads();

    // ---- scan: signs of logit at the 32 coarse samples ----
    unsigned msk = (C0 >= 0.0f) ? 1u : 0u;
    float cc0 = C0, cc1 = C1;
    float sf = 1.0f;
    #pragma unroll
    for (int s = 1; s < NSTEPS; ++s) {
        float2 ab = *(const float2*)&sAB[s][tid][0];
        cc1 += ab.x;
        cc0 += ab.y;
        float L = fmaf(cc1, sf, cc0);
        msk |= (L >= 0.0f) ? (1u << s) : 0u;
        sf += 1.0f;
    }

    // first free->occupied crossing: f[s]<0 && f[s+1]>=0
    unsigned cand = (~msk & (msk >> 1)) & 0x7FFFFFFFu;
    bool found = cand != 0u;
    int sstar = found ? __builtin_ctz(cand) : 0;   // ref: argmax(all-false)=0
    found = found && mask_int;

    // ---- bracket + secant: identical to R5's passing path ----
    auto logit2 = [&](float dA, float dB, float& lA, float& lB) {
        f2 dvA = (f2){dA, dA}, dvB = (f2){dB, dB};
        f2 aA0 = z2, aA1 = z2, aB0 = z2, aB1 = z2;
        #pragma unroll
        for (int h = 0; h < HDIM / 2; h += 2) {
            f2 xA0 = __builtin_elementwise_fma(dvA, rW[h + 0], cW[h + 0]);
            f2 xB0 = __builtin_elementwise_fma(dvB, rW[h + 0], cW[h + 0]);
            f2 xA1 = __builtin_elementwise_fma(dvA, rW[h + 1], cW[h + 1]);
            f2 xB1 = __builtin_elementwise_fma(dvB, rW[h + 1], cW[h + 1]);
            aA0 = __builtin_elementwise_fma(__builtin_elementwise_max(xA0, z2), w2[h + 0], aA0);
            aB0 = __builtin_elementwise_fma(__builtin_elementwise_max(xB0, z2), w2[h + 0], aB0);
            aA1 = __builtin_elementwise_fma(__builtin_elementwise_max(xA1, z2), w2[h + 1], aA1);
            aB1 = __builtin_elementwise_fma(__builtin_elementwise_max(xB1, z2), w2[h + 1], aB1);
        }
        f2 sA = aA0 + aA1, sB = aB0 + aB1;
        lA = (sA.x + sA.y) + B2;
        lB = (sB.x + sB.y) + B2;
    };
    auto logit = [&](float d) -> float {
        f2 dv = (f2){d, d};
        f2 a0 = z2, a1 = z2, a2 = z2, a3 = z2;
        #pragma unroll
        for (int h = 0; h < HDIM / 2; h += 4) {
            f2 x0 = __builtin_elementwise_fma(dv, rW[h + 0], cW[h + 0]);
            f2 x1 = __builtin_elementwise_fma(dv, rW[h + 1], cW[h + 1]);
            f2 x2 = __builtin_elementwise_fma(dv, rW[h + 2], cW[h + 2]);
            f2 x3 = __builtin_elementwise_fma(dv, rW[h + 3], cW[h + 3]);
            a0 = __builtin_elementwise_fma(__builtin_elementwise_max(x0, z2), w2[h + 0], a0);
            a1 = __builtin_elementwise_fma(__builtin_elementwise_max(x1, z2), w2[h + 1], a1);
            a2 = __builtin_elementwise_fma(__builtin_elementwise_max(x2, z2), w2[h + 2], a2);
            a3 = __builtin_elementwise_fma(__builtin_elementwise_max(x3, z2), w2[h + 3], a3);
        }
        f2 aa = (a0 + a1) + (a2 + a3);
        return (aa.x + aa.y) + B2;
    };
    auto sigm = [](float x) -> float {
        float e = __expf(-x);
        return __builtin_amdgcn_rcpf(1.0f + e);
    };

    float tlo = (float)sstar * STEPC;
    float thi = (float)(sstar + 1) * STEPC;
    float d_lo = NEARV * (1.0f - tlo) + farv * tlo;
    float d_hi = NEARV * (1.0f - thi) + farv * thi;
    float f_lo, f_hi;                 // logit-space secant state
    logit2(d_lo, d_hi, f_lo, f_hi);

    #pragma unroll 1
    for (int it = 0; it < NSECANT; ++it) {
        float den = f_hi - f_lo;
        den = (fabsf(den) < EPSV) ? EPSV : den;
        float dm = d_lo - f_lo * (d_hi - d_lo) * __builtin_amdgcn_rcpf(den);
        float fm = logit(dm);
        bool neg = fm < 0.0f;
        d_lo = neg ? dm : d_lo;
        f_lo = neg ? fm : f_lo;
        d_hi = neg ? d_hi : dm;
        f_hi = neg ? f_hi : fm;
    }
    float den = f_hi - f_lo;
    den = (fabsf(den) < EPSV) ? EPSV : den;
    float d_mid = d_lo - f_lo * (d_hi - d_lo) * __builtin_amdgcn_rcpf(den);

    float d_pred = found ? d_mid : 0.0f;
    float occ_s = sigm(logit(d_pred));
    float occ_surf = found ? occ_s : 0.0f;

    if (r < P) {
        out[r]     = d_pred;
        out[P + r] = occ_surf;
    }
}

extern "C" void kernel_launch(void* const* d_in, const int* in_sizes, int n_in,
                              void* d_out, int out_size, void* d_ws, size_t ws_size,
                              hipStream_t stream) {
    const float* cam_loc  = (const float*)d_in[0];
    const float* ray_dirs = (const float*)d_in[1];
    const float* W1       = (const float*)d_in[2];
    const float* b1       = (const float*)d_in[3];
    const float* W2       = (const float*)d_in[4];
    const float* b2       = (const float*)d_in[5];
    float* out = (float*)d_out;

    const int P = in_sizes[1] / 3;
    const int block = 256;
    const int grid = (P + block - 1) / block;
    unisurf_kernel<<<grid, block, 0, stream>>>(cam_loc, ray_dirs, W1, b1, W2, b2, out, P);
}

// Round 9
// 25.787 us; speedup vs baseline: 2.0295x; 2.0295x over previous
//
#include <hip/hip_runtime.h>
#include <math.h>

#define HDIM 32
#define NSTEPS 32
#define NSECANT 8
#define RADIUSV 1.0f
#define NEARV 0.5f
#define TAUV 0.5f
#define EPSV 1e-6f

typedef float f2 __attribute__((ext_vector_type(2)));

__global__ __launch_bounds__(256, 2) void unisurf_kernel(
    const float* __restrict__ cam_loc,   // [3]
    const float* __restrict__ ray_dirs,  // [P*3]
    const float* __restrict__ W1,        // [3*HDIM]
    const float* __restrict__ b1,        // [HDIM]
    const float* __restrict__ W2,        // [HDIM]
    const float* __restrict__ b2,        // [1]
    float* __restrict__ out,             // [2*P]: d_pred then occ_surf
    int P)
{
    __shared__ float4 sW[HDIM];   // (w0, w1, w2, b1) per hidden unit
    __shared__ float  sCW[HDIM];  // cam·W1 + b1  (ray-independent)
    __shared__ float  sW2[HDIM];
    __shared__ float  sB2;

    const int tid = threadIdx.x;
    if (tid < HDIM) {
        float c0 = cam_loc[0], c1 = cam_loc[1], c2l = cam_loc[2];
        float4 w4 = make_float4(W1[tid], W1[HDIM + tid], W1[2 * HDIM + tid], b1[tid]);
        sW[tid] = w4;
        sCW[tid] = c0 * w4.x + c1 * w4.y + c2l * w4.z + w4.w;
        sW2[tid] = W2[tid];
        if (tid == 0) sB2 = b2[0];
    }
    __syncthreads();

    const int r = blockIdx.x * blockDim.x + tid;
    if (r >= P) return;

    // camera (wave-uniform)
    const float cx = cam_loc[0], cy = cam_loc[1], cz = cam_loc[2];

    // ray load + fast normalize
    float dx = ray_dirs[3 * r + 0];
    float dy = ray_dirs[3 * r + 1];
    float dz = ray_dirs[3 * r + 2];
    float inv = __builtin_amdgcn_rsqf(dx * dx + dy * dy + dz * dz);
    float rx = dx * inv, ry = dy * inv, rz = dz * inv;

    // sphere intersection
    float rcd = rx * cx + ry * cy + rz * cz;
    float c2  = cx * cx + cy * cy + cz * cz;
    float us  = rcd * rcd - (c2 - RADIUSV * RADIUSV);
    bool  mask_int = us > 0.0f;
    float s_sq = mask_int ? sqrtf(us) : 0.0f;
    float far_raw = mask_int ? fmaxf(s_sq - rcd, 0.0f) : 0.0f;
    float farv = fmaxf(far_raw, NEARV + EPSV);

    // factored MLP per ray: a_h(d) = cW_h + d*rW_h
    // q*relu(a) == 0.5*(q*a + q*|a|) exactly =>
    // logit(d) = [B2 + 0.5*(Q0 + d*Q1)] + 0.5 * sum_h q_h*|a_h(d)|
    //          = fma(0.5, AbsSum, fma(d, L1, L0))
    f2 rW2[HDIM / 2], cW2[HDIM / 2], w2[HDIM / 2];
    #pragma unroll
    for (int h = 0; h < HDIM / 2; ++h) {
        float4 wa = sW[2 * h], wb = sW[2 * h + 1];
        rW2[h] = (f2){rx * wa.x + ry * wa.y + rz * wa.z,
                      rx * wb.x + ry * wb.y + rz * wb.z};
        cW2[h] = (f2){sCW[2 * h], sCW[2 * h + 1]};
        w2[h]  = (f2){sW2[2 * h], sW2[2 * h + 1]};
    }
    const float B2 = sB2;
    const f2 z2 = (f2){0.0f, 0.0f};

    // linear part: Q0 = sum q*cW, Q1 = sum q*rW (once per ray)
    f2 qc = z2, qr = z2;
    #pragma unroll
    for (int h = 0; h < HDIM / 2; ++h) {
        qc = __builtin_elementwise_fma(w2[h], cW2[h], qc);
        qr = __builtin_elementwise_fma(w2[h], rW2[h], qr);
    }
    const float L0 = fmaf(0.5f, qc.x + qc.y, B2);
    const float L1 = 0.5f * (qr.x + qr.y);

    // ---- abs-trick logit evals ----
    // 4 interleaved evals, 2 acc chains each
    auto alog4 = [&](float d0, float d1, float d2v, float d3,
                     float& l0, float& l1, float& l2, float& l3) {
        f2 dv0 = (f2){d0, d0}, dv1 = (f2){d1, d1};
        f2 dv2 = (f2){d2v, d2v}, dv3 = (f2){d3, d3};
        float a0a = 0.f, a0b = 0.f, a1a = 0.f, a1b = 0.f;
        float a2a = 0.f, a2b = 0.f, a3a = 0.f, a3b = 0.f;
        #pragma unroll
        for (int h = 0; h < HDIM / 2; h += 2) {
            f2 x0a = __builtin_elementwise_fma(dv0, rW2[h + 0], cW2[h + 0]);
            f2 x1a = __builtin_elementwise_fma(dv1, rW2[h + 0], cW2[h + 0]);
            f2 x2a = __builtin_elementwise_fma(dv2, rW2[h + 0], cW2[h + 0]);
            f2 x3a = __builtin_elementwise_fma(dv3, rW2[h + 0], cW2[h + 0]);
            f2 x0b = __builtin_elementwise_fma(dv0, rW2[h + 1], cW2[h + 1]);
            f2 x1b = __builtin_elementwise_fma(dv1, rW2[h + 1], cW2[h + 1]);
            f2 x2b = __builtin_elementwise_fma(dv2, rW2[h + 1], cW2[h + 1]);
            f2 x3b = __builtin_elementwise_fma(dv3, rW2[h + 1], cW2[h + 1]);
            float qx0 = w2[h + 0].x, qy0 = w2[h + 0].y;
            float qx1 = w2[h + 1].x, qy1 = w2[h + 1].y;
            a0a = fmaf(qx0, fabsf(x0a.x), a0a); a0a = fmaf(qy0, fabsf(x0a.y), a0a);
            a1a = fmaf(qx0, fabsf(x1a.x), a1a); a1a = fmaf(qy0, fabsf(x1a.y), a1a);
            a2a = fmaf(qx0, fabsf(x2a.x), a2a); a2a = fmaf(qy0, fabsf(x2a.y), a2a);
            a3a = fmaf(qx0, fabsf(x3a.x), a3a); a3a = fmaf(qy0, fabsf(x3a.y), a3a);
            a0b = fmaf(qx1, fabsf(x0b.x), a0b); a0b = fmaf(qy1, fabsf(x0b.y), a0b);
            a1b = fmaf(qx1, fabsf(x1b.x), a1b); a1b = fmaf(qy1, fabsf(x1b.y), a1b);
            a2b = fmaf(qx1, fabsf(x2b.x), a2b); a2b = fmaf(qy1, fabsf(x2b.y), a2b);
            a3b = fmaf(qx1, fabsf(x3b.x), a3b); a3b = fmaf(qy1, fabsf(x3b.y), a3b);
        }
        l0 = fmaf(0.5f, a0a + a0b, fmaf(d0, L1, L0));
        l1 = fmaf(0.5f, a1a + a1b, fmaf(d1, L1, L0));
        l2 = fmaf(0.5f, a2a + a2b, fmaf(d2v, L1, L0));
        l3 = fmaf(0.5f, a3a + a3b, fmaf(d3, L1, L0));
    };
    // 2 interleaved evals, 2 chains each
    auto alog2 = [&](float dA, float dB, float& lA, float& lB) {
        f2 dvA = (f2){dA, dA}, dvB = (f2){dB, dB};
        float aAa = 0.f, aAb = 0.f, aBa = 0.f, aBb = 0.f;
        #pragma unroll
        for (int h = 0; h < HDIM / 2; h += 2) {
            f2 xAa = __builtin_elementwise_fma(dvA, rW2[h + 0], cW2[h + 0]);
            f2 xBa = __builtin_elementwise_fma(dvB, rW2[h + 0], cW2[h + 0]);
            f2 xAb = __builtin_elementwise_fma(dvA, rW2[h + 1], cW2[h + 1]);
            f2 xBb = __builtin_elementwise_fma(dvB, rW2[h + 1], cW2[h + 1]);
            float qx0 = w2[h + 0].x, qy0 = w2[h + 0].y;
            float qx1 = w2[h + 1].x, qy1 = w2[h + 1].y;
            aAa = fmaf(qx0, fabsf(xAa.x), aAa); aAa = fmaf(qy0, fabsf(xAa.y), aAa);
            aBa = fmaf(qx0, fabsf(xBa.x), aBa); aBa = fmaf(qy0, fabsf(xBa.y), aBa);
            aAb = fmaf(qx1, fabsf(xAb.x), aAb); aAb = fmaf(qy1, fabsf(xAb.y), aAb);
            aBb = fmaf(qx1, fabsf(xBb.x), aBb); aBb = fmaf(qy1, fabsf(xBb.y), aBb);
        }
        lA = fmaf(0.5f, aAa + aAb, fmaf(dA, L1, L0));
        lB = fmaf(0.5f, aBa + aBb, fmaf(dB, L1, L0));
    };
    // single eval, 4 chains
    auto alog1 = [&](float d) -> float {
        f2 dv = (f2){d, d};
        float a0 = 0.f, a1 = 0.f, a2 = 0.f, a3 = 0.f;
        #pragma unroll
        for (int h = 0; h < HDIM / 2; h += 4) {
            f2 x0 = __builtin_elementwise_fma(dv, rW2[h + 0], cW2[h + 0]);
            f2 x1 = __builtin_elementwise_fma(dv, rW2[h + 1], cW2[h + 1]);
            f2 x2 = __builtin_elementwise_fma(dv, rW2[h + 2], cW2[h + 2]);
            f2 x3 = __builtin_elementwise_fma(dv, rW2[h + 3], cW2[h + 3]);
            a0 = fmaf(w2[h + 0].x, fabsf(x0.x), a0); a0 = fmaf(w2[h + 0].y, fabsf(x0.y), a0);
            a1 = fmaf(w2[h + 1].x, fabsf(x1.x), a1); a1 = fmaf(w2[h + 1].y, fabsf(x1.y), a1);
            a2 = fmaf(w2[h + 2].x, fabsf(x2.x), a2); a2 = fmaf(w2[h + 2].y, fabsf(x2.y), a2);
            a3 = fmaf(w2[h + 3].x, fabsf(x3.x), a3); a3 = fmaf(w2[h + 3].y, fabsf(x3.y), a3);
        }
        return fmaf(0.5f, (a0 + a1) + (a2 + a3), fmaf(d, L1, L0));
    };
    auto sigm = [](float x) -> float {   // fast sigmoid: v_exp + v_rcp
        float e = __expf(-x);
        return __builtin_amdgcn_rcpf(1.0f + e);
    };

    const float STEPC = 0.03225806451612903f;  // fl(1/31)
    const float DD = (farv - NEARV) * STEPC;   // per-step d increment

    // coarse march: 8 iters x 4 interleaved evals; bit s of msk = (logit_s >= 0)
    unsigned msk = 0u;
    #pragma unroll 1
    for (int k = 0; k < 8; ++k) {
        float dd0 = fmaf((float)k, DD, NEARV);
        float dd1 = fmaf((float)(k + 8), DD, NEARV);
        float dd2 = fmaf((float)(k + 16), DD, NEARV);
        float dd3 = fmaf((float)(k + 24), DD, NEARV);
        float l0, l1, l2, l3;
        alog4(dd0, dd1, dd2, dd3, l0, l1, l2, l3);
        msk |= (l0 >= 0.0f) ? (1u << k) : 0u;
        msk |= (l1 >= 0.0f) ? (1u << (k + 8)) : 0u;
        msk |= (l2 >= 0.0f) ? (1u << (k + 16)) : 0u;
        msk |= (l3 >= 0.0f) ? (1u << (k + 24)) : 0u;
    }

    // first free->occupied crossing: f[s]<0 && f[s+1]>=0
    unsigned cand = (~msk & (msk >> 1)) & 0x7FFFFFFFu;
    bool found = cand != 0u;
    int sstar = found ? __builtin_ctz(cand) : 0;   // ref: argmax(all-false)=0
    found = found && mask_int;

    // bracket endpoints (reference-style lerp, exact)
    float tlo = (float)sstar * STEPC;
    float thi = (float)(sstar + 1) * STEPC;
    float d_lo = NEARV * (1.0f - tlo) + farv * tlo;
    float d_hi = NEARV * (1.0f - thi) + farv * thi;
    float f_lo, f_hi;                 // logit-space secant state
    alog2(d_lo, d_hi, f_lo, f_hi);

    // secant refinement in logit space (root: sigmoid(l)=tau <=> l=0)
    #pragma unroll 1
    for (int it = 0; it < NSECANT; ++it) {
        float den = f_hi - f_lo;
        den = (fabsf(den) < EPSV) ? EPSV : den;
        float dm = d_lo - f_lo * (d_hi - d_lo) * __builtin_amdgcn_rcpf(den);
        float fm = alog1(dm);
        bool neg = fm < 0.0f;
        d_lo = neg ? dm : d_lo;
        f_lo = neg ? fm : f_lo;
        d_hi = neg ? d_hi : dm;
        f_hi = neg ? f_hi : fm;
    }
    float den = f_hi - f_lo;
    den = (fabsf(den) < EPSV) ? EPSV : den;
    float d_mid = d_lo - f_lo * (d_hi - d_lo) * __builtin_amdgcn_rcpf(den);

    float d_pred = found ? d_mid : 0.0f;
    float occ_s = sigm(alog1(d_pred));
    float occ_surf = found ? occ_s : 0.0f;

    out[r]     = d_pred;
    out[P + r] = occ_surf;
}

extern "C" void kernel_launch(void* const* d_in, const int* in_sizes, int n_in,
                              void* d_out, int out_size, void* d_ws, size_t ws_size,
                              hipStream_t stream) {
    const float* cam_loc  = (const float*)d_in[0];
    const float* ray_dirs = (const float*)d_in[1];
    const float* W1       = (const float*)d_in[2];
    const float* b1       = (const float*)d_in[3];
    const float* W2       = (const float*)d_in[4];
    const float* b2       = (const float*)d_in[5];
    float* out = (float*)d_out;

    const int P = in_sizes[1] / 3;
    const int block = 256;
    const int grid = (P + block - 1) / block;
    unisurf_kernel<<<grid, block, 0, stream>>>(cam_loc, ray_dirs, W1, b1, W2, b2, out, P);
}

// Round 10
// 19.305 us; speedup vs baseline: 2.7109x; 1.3358x over previous
//
#include <hip/hip_runtime.h>
#include <math.h>

#define HDIM 32
#define NSTEPS 32
#define NSECANT 8
#define RADIUSV 1.0f
#define NEARV 0.5f
#define TAUV 0.5f
#define EPSV 1e-6f

typedef float f2 __attribute__((ext_vector_type(2)));

__global__ __launch_bounds__(256, 2) void unisurf_kernel(
    const float* __restrict__ cam_loc,   // [3]
    const float* __restrict__ ray_dirs,  // [P*3]
    const float* __restrict__ W1,        // [3*HDIM]
    const float* __restrict__ b1,        // [HDIM]
    const float* __restrict__ W2,        // [HDIM]
    const float* __restrict__ b2,        // [1]
    float* __restrict__ out,             // [2*P]: d_pred then occ_surf
    int P)
{
    __shared__ float4 sW[HDIM];   // (w0, w1, w2, b1) per hidden unit
    __shared__ float  sCW[HDIM];  // cam·W1 + b1  (ray-independent)
    __shared__ float  sW2[HDIM];
    __shared__ float  sB2;

    const int tid = threadIdx.x;
    if (tid < HDIM) {
        float c0 = cam_loc[0], c1 = cam_loc[1], c2l = cam_loc[2];
        float4 w4 = make_float4(W1[tid], W1[HDIM + tid], W1[2 * HDIM + tid], b1[tid]);
        sW[tid] = w4;
        sCW[tid] = c0 * w4.x + c1 * w4.y + c2l * w4.z + w4.w;
        sW2[tid] = W2[tid];
        if (tid == 0) sB2 = b2[0];
    }
    __syncthreads();

    const int r = blockIdx.x * blockDim.x + tid;
    if (r >= P) return;

    // camera (wave-uniform)
    const float cx = cam_loc[0], cy = cam_loc[1], cz = cam_loc[2];

    // ray load + fast normalize (rsq ~1e-7 rel; threshold 3.5e-2)
    float dx = ray_dirs[3 * r + 0];
    float dy = ray_dirs[3 * r + 1];
    float dz = ray_dirs[3 * r + 2];
    float inv = __builtin_amdgcn_rsqf(dx * dx + dy * dy + dz * dz);
    float rx = dx * inv, ry = dy * inv, rz = dz * inv;

    // sphere intersection
    float rcd = rx * cx + ry * cy + rz * cz;
    float c2  = cx * cx + cy * cy + cz * cz;
    float us  = rcd * rcd - (c2 - RADIUSV * RADIUSV);
    bool  mask_int = us > 0.0f;
    float s_sq = mask_int ? sqrtf(us) : 0.0f;
    float far_raw = mask_int ? fmaxf(s_sq - rcd, 0.0f) : 0.0f;
    float farv = fmaxf(far_raw, NEARV + EPSV);

    // per-ray factored MLP: a_h(d) = cW[h] + d*rW[h]; logit = Σ relu(a)*w2 + B2
    // cW comes precomputed from LDS; rW = r·W1 computed here.
    f2 rW[HDIM / 2], cW[HDIM / 2], w2[HDIM / 2];
    #pragma unroll
    for (int h = 0; h < HDIM / 2; ++h) {
        float4 wa = sW[2 * h], wb = sW[2 * h + 1];
        rW[h] = (f2){rx * wa.x + ry * wa.y + rz * wa.z,
                     rx * wb.x + ry * wb.y + rz * wb.z};
        cW[h] = (f2){sCW[2 * h], sCW[2 * h + 1]};
        w2[h] = (f2){sW2[2 * h], sW2[2 * h + 1]};
    }
    const float B2 = sB2;
    const f2 z2 = (f2){0.0f, 0.0f};

    // four independent logit evals, instruction-interleaved (2 acc chains each)
    auto logit4 = [&](float d0, float d1, float d2v, float d3,
                      float& l0, float& l1, float& l2, float& l3) {
        f2 dv0 = (f2){d0, d0}, dv1 = (f2){d1, d1};
        f2 dv2 = (f2){d2v, d2v}, dv3 = (f2){d3, d3};
        f2 a0a = z2, a0b = z2, a1a = z2, a1b = z2;
        f2 a2a = z2, a2b = z2, a3a = z2, a3b = z2;
        #pragma unroll
        for (int h = 0; h < HDIM / 2; h += 2) {
            f2 x0a = __builtin_elementwise_fma(dv0, rW[h + 0], cW[h + 0]);
            f2 x1a = __builtin_elementwise_fma(dv1, rW[h + 0], cW[h + 0]);
            f2 x2a = __builtin_elementwise_fma(dv2, rW[h + 0], cW[h + 0]);
            f2 x3a = __builtin_elementwise_fma(dv3, rW[h + 0], cW[h + 0]);
            f2 x0b = __builtin_elementwise_fma(dv0, rW[h + 1], cW[h + 1]);
            f2 x1b = __builtin_elementwise_fma(dv1, rW[h + 1], cW[h + 1]);
            f2 x2b = __builtin_elementwise_fma(dv2, rW[h + 1], cW[h + 1]);
            f2 x3b = __builtin_elementwise_fma(dv3, rW[h + 1], cW[h + 1]);
            a0a = __builtin_elementwise_fma(__builtin_elementwise_max(x0a, z2), w2[h + 0], a0a);
            a1a = __builtin_elementwise_fma(__builtin_elementwise_max(x1a, z2), w2[h + 0], a1a);
            a2a = __builtin_elementwise_fma(__builtin_elementwise_max(x2a, z2), w2[h + 0], a2a);
            a3a = __builtin_elementwise_fma(__builtin_elementwise_max(x3a, z2), w2[h + 0], a3a);
            a0b = __builtin_elementwise_fma(__builtin_elementwise_max(x0b, z2), w2[h + 1], a0b);
            a1b = __builtin_elementwise_fma(__builtin_elementwise_max(x1b, z2), w2[h + 1], a1b);
            a2b = __builtin_elementwise_fma(__builtin_elementwise_max(x2b, z2), w2[h + 1], a2b);
            a3b = __builtin_elementwise_fma(__builtin_elementwise_max(x3b, z2), w2[h + 1], a3b);
        }
        f2 s0 = a0a + a0b, s1 = a1a + a1b, s2 = a2a + a2b, s3 = a3a + a3b;
        l0 = (s0.x + s0.y) + B2;
        l1 = (s1.x + s1.y) + B2;
        l2 = (s2.x + s2.y) + B2;
        l3 = (s3.x + s3.y) + B2;
    };
    // two interleaved evals (bracket)
    auto logit2 = [&](float dA, float dB, float& lA, float& lB) {
        f2 dvA = (f2){dA, dA}, dvB = (f2){dB, dB};
        f2 aA0 = z2, aA1 = z2, aB0 = z2, aB1 = z2;
        #pragma unroll
        for (int h = 0; h < HDIM / 2; h += 2) {
            f2 xA0 = __builtin_elementwise_fma(dvA, rW[h + 0], cW[h + 0]);
            f2 xB0 = __builtin_elementwise_fma(dvB, rW[h + 0], cW[h + 0]);
            f2 xA1 = __builtin_elementwise_fma(dvA, rW[h + 1], cW[h + 1]);
            f2 xB1 = __builtin_elementwise_fma(dvB, rW[h + 1], cW[h + 1]);
            aA0 = __builtin_elementwise_fma(__builtin_elementwise_max(xA0, z2), w2[h + 0], aA0);
            aB0 = __builtin_elementwise_fma(__builtin_elementwise_max(xB0, z2), w2[h + 0], aB0);
            aA1 = __builtin_elementwise_fma(__builtin_elementwise_max(xA1, z2), w2[h + 1], aA1);
            aB1 = __builtin_elementwise_fma(__builtin_elementwise_max(xB1, z2), w2[h + 1], aB1);
        }
        f2 sA = aA0 + aA1, sB = aB0 + aB1;
        lA = (sA.x + sA.y) + B2;
        lB = (sB.x + sB.y) + B2;
    };
    // single logit eval, 4 accumulator chains
    auto logit = [&](float d) -> float {
        f2 dv = (f2){d, d};
        f2 a0 = z2, a1 = z2, a2 = z2, a3 = z2;
        #pragma unroll
        for (int h = 0; h < HDIM / 2; h += 4) {
            f2 x0 = __builtin_elementwise_fma(dv, rW[h + 0], cW[h + 0]);
            f2 x1 = __builtin_elementwise_fma(dv, rW[h + 1], cW[h + 1]);
            f2 x2 = __builtin_elementwise_fma(dv, rW[h + 2], cW[h + 2]);
            f2 x3 = __builtin_elementwise_fma(dv, rW[h + 3], cW[h + 3]);
            a0 = __builtin_elementwise_fma(__builtin_elementwise_max(x0, z2), w2[h + 0], a0);
            a1 = __builtin_elementwise_fma(__builtin_elementwise_max(x1, z2), w2[h + 1], a1);
            a2 = __builtin_elementwise_fma(__builtin_elementwise_max(x2, z2), w2[h + 2], a2);
            a3 = __builtin_elementwise_fma(__builtin_elementwise_max(x3, z2), w2[h + 3], a3);
        }
        f2 aa = (a0 + a1) + (a2 + a3);
        return (aa.x + aa.y) + B2;
    };
    auto sigm = [](float x) -> float {
        float e = __expf(-x);
        return __builtin_amdgcn_rcpf(1.0f + e);
    };

    const float STEPC = 0.03225806451612903f;  // fl(1/31)

    // coarse march: 8 iters × 4 interleaved evals; bit s of msk = (logit_s >= 0)
    unsigned msk = 0u;
    #pragma unroll 1
    for (int k = 0; k < 8; ++k) {
        float t0 = (float)k * STEPC;
        float t1 = (float)(k + 8) * STEPC;
        float t2 = (float)(k + 16) * STEPC;
        float t3 = (float)(k + 24) * STEPC;
        float dd0 = NEARV * (1.0f - t0) + farv * t0;
        float dd1 = NEARV * (1.0f - t1) + farv * t1;
        float dd2 = NEARV * (1.0f - t2) + farv * t2;
        float dd3 = NEARV * (1.0f - t3) + farv * t3;
        float l0, l1, l2, l3;
        logit4(dd0, dd1, dd2, dd3, l0, l1, l2, l3);
        msk |= (l0 >= 0.0f) ? (1u << k) : 0u;
        msk |= (l1 >= 0.0f) ? (1u << (k + 8)) : 0u;
        msk |= (l2 >= 0.0f) ? (1u << (k + 16)) : 0u;
        msk |= (l3 >= 0.0f) ? (1u << (k + 24)) : 0u;
    }

    // first free->occupied crossing: f[s]<0 && f[s+1]>=0
    unsigned cand = (~msk & (msk >> 1)) & 0x7FFFFFFFu;
    bool found = cand != 0u;
    int sstar = found ? __builtin_ctz(cand) : 0;   // ref: argmax(all-false)=0
    found = found && mask_int;

    // bracket endpoints (exact reference-style lerp)
    float tlo = (float)sstar * STEPC;
    float thi = (float)(sstar + 1) * STEPC;
    float d_lo = NEARV * (1.0f - tlo) + farv * tlo;
    float d_hi = NEARV * (1.0f - thi) + farv * thi;
    float f_lo, f_hi;                 // logit-space secant state
    logit2(d_lo, d_hi, f_lo, f_hi);

    // secant refinement in logit space (same root: sigmoid(l)=tau <=> l=0)
    #pragma unroll 1
    for (int it = 0; it < NSECANT; ++it) {
        float den = f_hi - f_lo;
        den = (fabsf(den) < EPSV) ? EPSV : den;
        float dm = d_lo - f_lo * (d_hi - d_lo) * __builtin_amdgcn_rcpf(den);
        float fm = logit(dm);
        bool neg = fm < 0.0f;
        d_lo = neg ? dm : d_lo;
        f_lo = neg ? fm : f_lo;
        d_hi = neg ? d_hi : dm;
        f_hi = neg ? f_hi : fm;
    }
    float den = f_hi - f_lo;
    den = (fabsf(den) < EPSV) ? EPSV : den;
    float d_mid = d_lo - f_lo * (d_hi - d_lo) * __builtin_amdgcn_rcpf(den);

    float d_pred = found ? d_mid : 0.0f;
    float occ_s = sigm(logit(d_pred));
    float occ_surf = found ? occ_s : 0.0f;

    out[r]     = d_pred;
    out[P + r] = occ_surf;
}

extern "C" void kernel_launch(void* const* d_in, const int* in_sizes, int n_in,
                              void* d_out, int out_size, void* d_ws, size_t ws_size,
                              hipStream_t stream) {
    const float* cam_loc  = (const float*)d_in[0];
    const float* ray_dirs = (const float*)d_in[1];
    const float* W1       = (const float*)d_in[2];
    const float* b1       = (const float*)d_in[3];
    const float* W2       = (const float*)d_in[4];
    const float* b2       = (const float*)d_in[5];
    float* out = (float*)d_out;

    const int P = in_sizes[1] / 3;
    const int block = 256;
    const int grid = (P + block - 1) / block;
    unisurf_kernel<<<grid, block, 0, stream>>>(cam_loc, ray_dirs, W1, b1, W2, b2, out, P);
}